// Round 2
// baseline (648.909 us; speedup 1.0000x reference)
//
#include <hip/hip_runtime.h>

using bf16x8 = __attribute__((ext_vector_type(8))) __bf16;
using f32x4  = __attribute__((ext_vector_type(4))) float;

#define BM 128
#define BN 128
#define BK 32

// Async global->LDS, 16B per lane. LDS dest is wave-uniform base + lane*16
// (m104/m108): pass the wave's base, per-lane global src.
__device__ __forceinline__ void async_load16(const void* g, void* l) {
    __builtin_amdgcn_global_load_lds(
        (const __attribute__((address_space(1))) unsigned int*)g,
        (__attribute__((address_space(3))) unsigned int*)l,
        16, 0, 0);
}

// ------------------------------------------------------------- fused prep
// Region 0: x fp32 -> bf16.  Region 1: w_q int32 -> (q-128)*scale -> bf16.
// One launch, 8 elems/thread, 32 B/lane loads + 16 B/lane stores (coalesced).
__global__ __launch_bounds__(256) void prep_kernel(
    const float* __restrict__ x, const int* __restrict__ wq,
    const float* __restrict__ sc, __bf16* __restrict__ xb,
    __bf16* __restrict__ wb, int xc, int wc, int I) {
    int c = blockIdx.x * 256 + threadIdx.x;
    if (c < xc) {
        const int i = c * 8;
        const float4 a = *(const float4*)(x + i);
        const float4 b = *(const float4*)(x + i + 4);
        bf16x8 v;
        v[0] = (__bf16)a.x; v[1] = (__bf16)a.y; v[2] = (__bf16)a.z; v[3] = (__bf16)a.w;
        v[4] = (__bf16)b.x; v[5] = (__bf16)b.y; v[6] = (__bf16)b.z; v[7] = (__bf16)b.w;
        *(bf16x8*)(xb + i) = v;
    } else {
        c -= xc;
        if (c >= wc) return;
        const int i = c * 8;
        const int row = i / I;
        const int col = i - row * I;
        // 8 consecutive elements never cross a 32-quant scale block (8 | 32)
        const float s = sc[row * (I >> 5) + (col >> 5)];
        const int4 a = *(const int4*)(wq + i);
        const int4 b = *(const int4*)(wq + i + 4);
        bf16x8 v;
        v[0] = (__bf16)((float)(a.x - 128) * s);
        v[1] = (__bf16)((float)(a.y - 128) * s);
        v[2] = (__bf16)((float)(a.z - 128) * s);
        v[3] = (__bf16)((float)(a.w - 128) * s);
        v[4] = (__bf16)((float)(b.x - 128) * s);
        v[5] = (__bf16)((float)(b.y - 128) * s);
        v[6] = (__bf16)((float)(b.z - 128) * s);
        v[7] = (__bf16)((float)(b.w - 128) * s);
        *(bf16x8*)(wb + i) = v;
    }
}

// ---------------------------------------------------------------- main GEMM
// C[M,N] = A[M,K] * B[N,K]^T + bias[N]; A,B bf16, C fp32.
// m97 structure: 128x128x32 tile, 256 thr (4 waves, 2x2 wave grid, 64x64/wave),
// global_load_lds width=16 staging, 16x 16x16x32 MFMA per wave per K-iter.
// 1D grid + GROUP_M=8 swizzle: consecutive blocks walk down M within a group,
// so temporally-concurrent blocks share A/B k-slices in per-XCD L2.
__global__ __launch_bounds__(256) void gemm_bf16_bt(
    const __bf16* __restrict__ A, const __bf16* __restrict__ B,
    const float* __restrict__ bias, float* __restrict__ C,
    int M, int N, int K, int nbm, int nbn) {
    __shared__ __bf16 ldsA[BM * BK];   // 8 KiB, rows of 64 B (k-contiguous)
    __shared__ __bf16 ldsB[BN * BK];   // 8 KiB

    // ---- GROUP_M swizzle (Triton-style), computed once per block
    const int GROUP = 8;
    const int pid   = blockIdx.x;
    const int width = GROUP * nbn;
    const int gid   = pid / width;
    const int first = gid * GROUP;
    const int gsz   = min(nbm - first, GROUP);
    const int pid_m = first + (pid % gsz);
    const int pid_n = (pid % width) / gsz;

    const int tid  = threadIdx.x;
    const int wave = tid >> 6;
    const int lane = tid & 63;
    const int r = lane & 15;          // MFMA A/B operand: m/n = lane&15
    const int q = lane >> 4;          // k = q*8 + j
    const int wm = (wave >> 1) * 64;
    const int wn = (wave & 1) * 64;

    const int row0 = pid_m * BM;
    const int col0 = pid_n * BN;
    const size_t rowBytes = (size_t)K * sizeof(__bf16);

    // Staging assignment: flat tile byte b = (it*256 + tid)*16,
    // tile row = b>>6 (64 B per row), in-row byte = b&63.
    const char* gA[2];
    const char* gB[2];
    char* lA[2];
    char* lB[2];
#pragma unroll
    for (int it = 0; it < 2; ++it) {
        const int b    = (it * 256 + tid) * 16;
        const int trow = b >> 6;
        const int tcol = b & 63;
        gA[it] = (const char*)A + (size_t)(row0 + trow) * rowBytes + tcol;
        gB[it] = (const char*)B + (size_t)(col0 + trow) * rowBytes + tcol;
        const int wb = (it * 256 + wave * 64) * 16;   // wave-uniform LDS base
        lA[it] = (char*)ldsA + wb;
        lB[it] = (char*)ldsB + wb;
    }

    // Loop-invariant LDS fragment pointers (16B-aligned -> ds_read_b128)
    const __bf16* ap[4];
    const __bf16* bp[4];
#pragma unroll
    for (int i = 0; i < 4; ++i) {
        ap[i] = ldsA + (wm + i * 16 + r) * BK + q * 8;
        bp[i] = ldsB + (wn + i * 16 + r) * BK + q * 8;
    }

    const f32x4 zero = {0.f, 0.f, 0.f, 0.f};
    f32x4 acc[4][4];
#pragma unroll
    for (int i = 0; i < 4; ++i)
#pragma unroll
        for (int j = 0; j < 4; ++j) acc[i][j] = zero;

    for (int k0 = 0; k0 < K; k0 += BK) {
#pragma unroll
        for (int it = 0; it < 2; ++it) {
            async_load16(gA[it], lA[it]);
            async_load16(gB[it], lB[it]);
            gA[it] += BK * sizeof(__bf16);
            gB[it] += BK * sizeof(__bf16);
        }
        __syncthreads();   // compiler emits s_waitcnt vmcnt(0) before s_barrier

        bf16x8 af[4], bf[4];
#pragma unroll
        for (int i = 0; i < 4; ++i) af[i] = *(const bf16x8*)ap[i];
#pragma unroll
        for (int j = 0; j < 4; ++j) bf[j] = *(const bf16x8*)bp[j];

#pragma unroll
        for (int i = 0; i < 4; ++i)
#pragma unroll
            for (int j = 0; j < 4; ++j)
                acc[i][j] = __builtin_amdgcn_mfma_f32_16x16x32_bf16(
                    af[i], bf[j], acc[i][j], 0, 0, 0);

        __syncthreads();
    }

    // Epilogue: C/D layout col=lane&15, row=quad*4+reg (m89/m91-verified).
#pragma unroll
    for (int j = 0; j < 4; ++j) {
        const int col = col0 + wn + j * 16 + r;
        const float bv = bias[col];
#pragma unroll
        for (int i = 0; i < 4; ++i) {
            const int row = row0 + wm + i * 16 + q * 4;
#pragma unroll
            for (int e = 0; e < 4; ++e)
                C[(size_t)(row + e) * N + col] = acc[i][j][e] + bv;
        }
    }
}

// ------------------------------------------------------- fallback (safety net)
__global__ void fallback_kernel(
    const float* __restrict__ x, const int* __restrict__ wq,
    const float* __restrict__ sc, const float* __restrict__ bias,
    float* __restrict__ out, int T, int O, int I) {
    int o = blockIdx.x * 16 + threadIdx.x;
    int t = blockIdx.y * 16 + threadIdx.y;
    if (o >= O || t >= T) return;
    const int nb = I >> 5;
    float s = 0.f;
    for (int b = 0; b < nb; ++b) {
        const float scv = sc[o * nb + b];
        float p = 0.f;
        for (int k = 0; k < 32; ++k)
            p += x[(size_t)t * I + b * 32 + k] *
                 (float)(wq[(size_t)o * I + b * 32 + k] - 128);
        s += scv * p;
    }
    out[(size_t)t * O + o] = s + bias[o];
}

// ---------------------------------------------------------------------- launch
extern "C" void kernel_launch(void* const* d_in, const int* in_sizes, int n_in,
                              void* d_out, int out_size, void* d_ws, size_t ws_size,
                              hipStream_t stream) {
    const float* x    = (const float*)d_in[0];
    const int*   wq   = (const int*)d_in[1];
    const float* sc   = (const float*)d_in[2];
    const float* bias = (const float*)d_in[3];
    float* out = (float*)d_out;

    const long long xn = in_sizes[0];
    const long long wn = in_sizes[1];
    const int O = in_sizes[3];
    const int I = (int)(wn / O);
    const int T = (int)(xn / I);

    const size_t xbBytes = (size_t)T * I * sizeof(__bf16);
    const size_t wbBytes = (size_t)O * I * sizeof(__bf16);

    const bool fast = (ws_size >= xbBytes + wbBytes) &&
                      (T % BM == 0) && (O % BN == 0) && (I % BK == 0) &&
                      ((I & 31) == 0) && ((T * I) % (8 * 256) == 0);

    if (!fast) {
        dim3 blk(16, 16);
        dim3 grd((O + 15) / 16, (T + 15) / 16);
        hipLaunchKernelGGL(fallback_kernel, grd, blk, 0, stream,
                           x, wq, sc, bias, out, T, O, I);
        return;
    }

    __bf16* xb = (__bf16*)d_ws;
    __bf16* wb = (__bf16*)((char*)d_ws + xbBytes);

    {
        const int xc = T * I / 8;
        const int wc = O * I / 8;
        const int blocks = (xc + wc + 255) / 256;
        hipLaunchKernelGGL(prep_kernel, dim3(blocks), dim3(256), 0, stream,
                           x, wq, sc, xb, wb, xc, wc, I);
    }
    {
        const int nbm = T / BM;
        const int nbn = O / BN;
        hipLaunchKernelGGL(gemm_bf16_bt, dim3(nbm * nbn), dim3(256), 0, stream,
                           xb, wb, bias, out, T, O, I, nbm, nbn);
    }
}

// Round 3
// 618.597 us; speedup vs baseline: 1.0490x; 1.0490x over previous
//
#include <hip/hip_runtime.h>

using bf16x8 = __attribute__((ext_vector_type(8))) __bf16;
using f32x4  = __attribute__((ext_vector_type(4))) float;

#define BM 128
#define BN 128
#define BK 64          // two 32-k sub-tiles behind ONE barrier
#define HALF_BYTES 8192  // one 128x32 bf16 sub-tile

// Async global->LDS, 16B per lane. LDS dest is wave-uniform base + lane*16
// (m104/m108): pass the wave's base, per-lane global src.
__device__ __forceinline__ void async_load16(const void* g, void* l) {
    __builtin_amdgcn_global_load_lds(
        (const __attribute__((address_space(1))) unsigned int*)g,
        (__attribute__((address_space(3))) unsigned int*)l,
        16, 0, 0);
}

// ------------------------------------------------------------- fused prep
// Region 0: x fp32 -> bf16.  Region 1: w_q int32 -> (q-128)*scale -> bf16.
__global__ __launch_bounds__(256) void prep_kernel(
    const float* __restrict__ x, const int* __restrict__ wq,
    const float* __restrict__ sc, __bf16* __restrict__ xb,
    __bf16* __restrict__ wb, int xc, int wc, int I) {
    int c = blockIdx.x * 256 + threadIdx.x;
    if (c < xc) {
        const int i = c * 8;
        const float4 a = *(const float4*)(x + i);
        const float4 b = *(const float4*)(x + i + 4);
        bf16x8 v;
        v[0] = (__bf16)a.x; v[1] = (__bf16)a.y; v[2] = (__bf16)a.z; v[3] = (__bf16)a.w;
        v[4] = (__bf16)b.x; v[5] = (__bf16)b.y; v[6] = (__bf16)b.z; v[7] = (__bf16)b.w;
        *(bf16x8*)(xb + i) = v;
    } else {
        c -= xc;
        if (c >= wc) return;
        const int i = c * 8;
        const int row = i / I;
        const int col = i - row * I;
        // 8 consecutive elements never cross a 32-quant scale block (8 | 32)
        const float s = sc[row * (I >> 5) + (col >> 5)];
        const int4 a = *(const int4*)(wq + i);
        const int4 b = *(const int4*)(wq + i + 4);
        bf16x8 v;
        v[0] = (__bf16)((float)(a.x - 128) * s);
        v[1] = (__bf16)((float)(a.y - 128) * s);
        v[2] = (__bf16)((float)(a.z - 128) * s);
        v[3] = (__bf16)((float)(a.w - 128) * s);
        v[4] = (__bf16)((float)(b.x - 128) * s);
        v[5] = (__bf16)((float)(b.y - 128) * s);
        v[6] = (__bf16)((float)(b.z - 128) * s);
        v[7] = (__bf16)((float)(b.w - 128) * s);
        *(bf16x8*)(wb + i) = v;
    }
}

// ---------------------------------------------------------------- main GEMM
// C[M,N] = A[M,K] * B[N,K]^T + bias[N]; A,B bf16, C fp32.
// m97 structure, BK=64 variant: per K-iter stage TWO 128x32 sub-tiles of A
// and B (each laid out exactly as the proven 64B-row BK=32 tile), ONE
// barrier, then 2x16 MFMAs. Halves the vmcnt(0)+barrier drain count.
// Grid: 2D, blockIdx.x = n-tile (fastest) -> per-XCD B-column residency in L2
// (round 2 showed disturbing this costs 3x cold FETCH).
__global__ __launch_bounds__(256) void gemm_bf16_bt(
    const __bf16* __restrict__ A, const __bf16* __restrict__ B,
    const float* __restrict__ bias, float* __restrict__ C,
    int M, int N, int K) {
    __shared__ __bf16 ldsA[2 * BM * 32];   // 16 KiB: two 64B-row sub-tiles
    __shared__ __bf16 ldsB[2 * BN * 32];   // 16 KiB

    const int tid  = threadIdx.x;
    const int wave = tid >> 6;
    const int lane = tid & 63;
    const int r = lane & 15;          // MFMA A/B operand: m/n = lane&15
    const int q = lane >> 4;          // k = q*8 + j
    const int wm = (wave >> 1) * 64;
    const int wn = (wave & 1) * 64;

    const int row0 = blockIdx.y * BM;
    const int col0 = blockIdx.x * BN;
    const size_t rowBytes = (size_t)K * sizeof(__bf16);

    // Staging assignment (per 32-k half): flat sub-tile byte b = (it*256+tid)*16,
    // sub-tile row = b>>6 (64 B per row), in-row byte = b&63.
    const char* gA[2];
    const char* gB[2];
    char* lA[2];
    char* lB[2];
#pragma unroll
    for (int it = 0; it < 2; ++it) {
        const int b    = (it * 256 + tid) * 16;
        const int trow = b >> 6;
        const int tcol = b & 63;
        gA[it] = (const char*)A + (size_t)(row0 + trow) * rowBytes + tcol;
        gB[it] = (const char*)B + (size_t)(col0 + trow) * rowBytes + tcol;
        const int wb = (it * 256 + wave * 64) * 16;   // wave-uniform LDS base
        lA[it] = (char*)ldsA + wb;
        lB[it] = (char*)ldsB + wb;
    }

    // Loop-invariant LDS fragment pointers (16B-aligned -> ds_read_b128)
    const __bf16* ap[4];
    const __bf16* bp[4];
#pragma unroll
    for (int i = 0; i < 4; ++i) {
        ap[i] = ldsA + (wm + i * 16 + r) * 32 + q * 8;
        bp[i] = ldsB + (wn + i * 16 + r) * 32 + q * 8;
    }

    const f32x4 zero = {0.f, 0.f, 0.f, 0.f};
    f32x4 acc[4][4];
#pragma unroll
    for (int i = 0; i < 4; ++i)
#pragma unroll
        for (int j = 0; j < 4; ++j) acc[i][j] = zero;

    for (int k0 = 0; k0 < K; k0 += BK) {
        // Stage both 32-k halves (8 outstanding lds-DMA loads), one barrier.
#pragma unroll
        for (int h = 0; h < 2; ++h)
#pragma unroll
            for (int it = 0; it < 2; ++it) {
                async_load16(gA[it] + h * 64, lA[it] + h * HALF_BYTES);
                async_load16(gB[it] + h * 64, lB[it] + h * HALF_BYTES);
            }
#pragma unroll
        for (int it = 0; it < 2; ++it) {
            gA[it] += BK * sizeof(__bf16);
            gB[it] += BK * sizeof(__bf16);
        }
        __syncthreads();   // single vmcnt(0) drain per 64-k step

#pragma unroll
        for (int h = 0; h < 2; ++h) {
            const int off = h * (HALF_BYTES / 2);   // bf16 elements
            bf16x8 af[4], bf[4];
#pragma unroll
            for (int i = 0; i < 4; ++i) af[i] = *(const bf16x8*)(ap[i] + off);
#pragma unroll
            for (int j = 0; j < 4; ++j) bf[j] = *(const bf16x8*)(bp[j] + off);

#pragma unroll
            for (int i = 0; i < 4; ++i)
#pragma unroll
                for (int j = 0; j < 4; ++j)
                    acc[i][j] = __builtin_amdgcn_mfma_f32_16x16x32_bf16(
                        af[i], bf[j], acc[i][j], 0, 0, 0);
        }

        __syncthreads();
    }

    // Epilogue: C/D layout col=lane&15, row=quad*4+reg (m89/m91-verified).
#pragma unroll
    for (int j = 0; j < 4; ++j) {
        const int col = col0 + wn + j * 16 + r;
        const float bv = bias[col];
#pragma unroll
        for (int i = 0; i < 4; ++i) {
            const int row = row0 + wm + i * 16 + q * 4;
#pragma unroll
            for (int e = 0; e < 4; ++e)
                C[(size_t)(row + e) * N + col] = acc[i][j][e] + bv;
        }
    }
}

// ------------------------------------------------------- fallback (safety net)
__global__ void fallback_kernel(
    const float* __restrict__ x, const int* __restrict__ wq,
    const float* __restrict__ sc, const float* __restrict__ bias,
    float* __restrict__ out, int T, int O, int I) {
    int o = blockIdx.x * 16 + threadIdx.x;
    int t = blockIdx.y * 16 + threadIdx.y;
    if (o >= O || t >= T) return;
    const int nb = I >> 5;
    float s = 0.f;
    for (int b = 0; b < nb; ++b) {
        const float scv = sc[o * nb + b];
        float p = 0.f;
        for (int k = 0; k < 32; ++k)
            p += x[(size_t)t * I + b * 32 + k] *
                 (float)(wq[(size_t)o * I + b * 32 + k] - 128);
        s += scv * p;
    }
    out[(size_t)t * O + o] = s + bias[o];
}

// ---------------------------------------------------------------------- launch
extern "C" void kernel_launch(void* const* d_in, const int* in_sizes, int n_in,
                              void* d_out, int out_size, void* d_ws, size_t ws_size,
                              hipStream_t stream) {
    const float* x    = (const float*)d_in[0];
    const int*   wq   = (const int*)d_in[1];
    const float* sc   = (const float*)d_in[2];
    const float* bias = (const float*)d_in[3];
    float* out = (float*)d_out;

    const long long xn = in_sizes[0];
    const long long wn = in_sizes[1];
    const int O = in_sizes[3];
    const int I = (int)(wn / O);
    const int T = (int)(xn / I);

    const size_t xbBytes = (size_t)T * I * sizeof(__bf16);
    const size_t wbBytes = (size_t)O * I * sizeof(__bf16);

    const bool fast = (ws_size >= xbBytes + wbBytes) &&
                      (T % BM == 0) && (O % BN == 0) && (I % BK == 0) &&
                      ((I & 31) == 0) && ((T * I) % (8 * 256) == 0);

    if (!fast) {
        dim3 blk(16, 16);
        dim3 grd((O + 15) / 16, (T + 15) / 16);
        hipLaunchKernelGGL(fallback_kernel, grd, blk, 0, stream,
                           x, wq, sc, bias, out, T, O, I);
        return;
    }

    __bf16* xb = (__bf16*)d_ws;
    __bf16* wb = (__bf16*)((char*)d_ws + xbBytes);

    {
        const int xc = T * I / 8;
        const int wc = O * I / 8;
        const int blocks = (xc + wc + 255) / 256;
        hipLaunchKernelGGL(prep_kernel, dim3(blocks), dim3(256), 0, stream,
                           x, wq, sc, xb, wb, xc, wc, I);
    }
    hipLaunchKernelGGL(gemm_bf16_bt, dim3(O / BN, T / BM), dim3(256), 0, stream,
                       xb, wb, bias, out, T, O, I);
}